// Round 3
// baseline (1025.134 us; speedup 1.0000x reference)
//
#include <hip/hip_runtime.h>

typedef unsigned short u16;
using bf16x8 = __attribute__((ext_vector_type(8))) __bf16;
using f32x4  = __attribute__((ext_vector_type(4))) float;

// B=2, T=2048, D=4096, H=32, HD=128, HKV=1. M = B*T = 4096 token rows.
// Inputs/outputs are FP32 (per reference). Internals are bf16 for MFMA.

__device__ __forceinline__ u16 f2b(float f) {
    union { float f; unsigned int i; } x; x.f = f;
    unsigned int i = x.i + (((x.i >> 16) & 1u) + 0x7fffu);  // RNE
    return (u16)(i >> 16);
}
__device__ __forceinline__ void gload_lds16(const u16* g, u16* l) {
    __builtin_amdgcn_global_load_lds((const __attribute__((address_space(1))) void*)g,
                                     (__attribute__((address_space(3))) void*)l, 16, 0, 0);
}

// ---- fp32 -> bf16 conversion (vectorized, 8 elems/thread) ----
__global__ __launch_bounds__(256) void cvt_f32_bf16(const float* __restrict__ in,
                                                    u16* __restrict__ out, int n) {
    int i = (blockIdx.x * 256 + threadIdx.x) * 8;
    if (i >= n) return;
    float4 a = *(const float4*)(in + i);
    float4 b = *(const float4*)(in + i + 4);
    union { u16 u[8]; uint4 v; } o;
    o.u[0] = f2b(a.x); o.u[1] = f2b(a.y); o.u[2] = f2b(a.z); o.u[3] = f2b(a.w);
    o.u[4] = f2b(b.x); o.u[5] = f2b(b.y); o.u[6] = f2b(b.z); o.u[7] = f2b(b.w);
    *(uint4*)(out + i) = o.v;
}

// ---- m97-style 128x128 tile gemm_bt core: C = A(128xK) * W(128xK)^T, K=4096 ----
__device__ __forceinline__ void gemm_core(const u16* __restrict__ Atile,
                                          const u16* __restrict__ Wtile,
                                          f32x4 acc[4][4], u16* sA, u16* sB, int t) {
    const int K = 4096;
    int lane = t & 63, wave = t >> 6;
    int wm = (wave & 1) * 64, wn = (wave >> 1) * 64;
    int r = lane & 15, qd = lane >> 4;
    int e0 = t * 8;            // thread's element slot in flattened 128x32 tile
    int sr0 = e0 >> 5;         // row (0..63), second call adds +64
    int sc0 = e0 & 31;
    for (int kt = 0; kt < K / 32; ++kt) {
        int k0 = kt * 32;
        gload_lds16(Atile + (size_t)sr0 * K + k0 + sc0,        sA + e0);
        gload_lds16(Atile + (size_t)(sr0 + 64) * K + k0 + sc0, sA + e0 + 2048);
        gload_lds16(Wtile + (size_t)sr0 * K + k0 + sc0,        sB + e0);
        gload_lds16(Wtile + (size_t)(sr0 + 64) * K + k0 + sc0, sB + e0 + 2048);
        __syncthreads();
        bf16x8 af[4], bfr[4];
#pragma unroll
        for (int mt = 0; mt < 4; ++mt) af[mt] = *(const bf16x8*)(sA + (wm + mt * 16 + r) * 32 + qd * 8);
#pragma unroll
        for (int nt = 0; nt < 4; ++nt) bfr[nt] = *(const bf16x8*)(sB + (wn + nt * 16 + r) * 32 + qd * 8);
#pragma unroll
        for (int mt = 0; mt < 4; ++mt)
#pragma unroll
            for (int nt = 0; nt < 4; ++nt)
                acc[mt][nt] = __builtin_amdgcn_mfma_f32_16x16x32_bf16(af[mt], bfr[nt], acc[mt][nt], 0, 0, 0);
        __syncthreads();
    }
}

// ---- fused QKV projection. grid (32, 34). col<32: Q. col==32: K. col==33: V (stored transposed) ----
__global__ __launch_bounds__(256) void qkv_gemm(
    const u16* __restrict__ x,
    const u16* __restrict__ wq, const float* __restrict__ wqb,
    const u16* __restrict__ wk, const float* __restrict__ wkb,
    const u16* __restrict__ wv, const float* __restrict__ wvb,
    u16* __restrict__ Qb, u16* __restrict__ Kb, u16* __restrict__ Vt) {
    __shared__ __align__(16) u16 sA[128 * 32];
    __shared__ __align__(16) u16 sB[128 * 32];
    int row0 = blockIdx.x * 128;
    int bn = blockIdx.y;
    const u16* W; const float* bias;
    if (bn < 32)       { W = wq + (size_t)bn * 128 * 4096; bias = wqb + bn * 128; }
    else if (bn == 32) { W = wk; bias = wkb; }
    else               { W = wv; bias = wvb; }
    int t = threadIdx.x;
    f32x4 acc[4][4];
#pragma unroll
    for (int mt = 0; mt < 4; ++mt)
#pragma unroll
        for (int nt = 0; nt < 4; ++nt) acc[mt][nt] = (f32x4){0.f, 0.f, 0.f, 0.f};
    gemm_core(x + (size_t)row0 * 4096, W, acc, sA, sB, t);
    int lane = t & 63, wave = t >> 6;
    int wm = (wave & 1) * 64, wn = (wave >> 1) * 64;
    int r = lane & 15, qd = lane >> 4;
#pragma unroll
    for (int nt = 0; nt < 4; ++nt) {
        float bv = bias[wn + nt * 16 + r];
#pragma unroll
        for (int mt = 0; mt < 4; ++mt)
#pragma unroll
            for (int j = 0; j < 4; ++j) {
                u16 ob = f2b(acc[mt][nt][j] + bv);
                int m = row0 + wm + mt * 16 + qd * 4 + j;
                int n = wn + nt * 16 + r;
                if (bn < 32)       Qb[(size_t)m * 4096 + bn * 128 + n] = ob;
                else if (bn == 32) Kb[(size_t)m * 128 + n] = ob;
                else               Vt[(size_t)n * 4096 + m] = ob;   // transposed store for flash PV
            }
    }
}

// ---- output projection: C(fp32) = A(bf16) * wo(bf16)^T + b(fp32). grid (32, 32) ----
__global__ __launch_bounds__(256) void out_gemm(
    const u16* __restrict__ A, const u16* __restrict__ W,
    const float* __restrict__ bias, float* __restrict__ C) {
    __shared__ __align__(16) u16 sA[128 * 32];
    __shared__ __align__(16) u16 sB[128 * 32];
    int row0 = blockIdx.x * 128;
    int col0 = blockIdx.y * 128;
    int t = threadIdx.x;
    f32x4 acc[4][4];
#pragma unroll
    for (int mt = 0; mt < 4; ++mt)
#pragma unroll
        for (int nt = 0; nt < 4; ++nt) acc[mt][nt] = (f32x4){0.f, 0.f, 0.f, 0.f};
    gemm_core(A + (size_t)row0 * 4096, W + (size_t)col0 * 4096, acc, sA, sB, t);
    int lane = t & 63, wave = t >> 6;
    int wm = (wave & 1) * 64, wn = (wave >> 1) * 64;
    int r = lane & 15, qd = lane >> 4;
#pragma unroll
    for (int nt = 0; nt < 4; ++nt) {
        float bv = bias[col0 + wn + nt * 16 + r];
#pragma unroll
        for (int mt = 0; mt < 4; ++mt)
#pragma unroll
            for (int j = 0; j < 4; ++j) {
                int m = row0 + wm + mt * 16 + qd * 4 + j;
                int n = col0 + wn + nt * 16 + r;
                C[(size_t)m * 4096 + n] = acc[mt][nt][j] + bv;
            }
    }
}

// ---- flash MQA attention. grid (16, 32, 2) = (q-tile, head, batch). 128 q rows/block, 64-kv tiles ----
#define LOG2E 1.4426950408889634f
__global__ __launch_bounds__(256, 2) void flash_mqa(
    const u16* __restrict__ Qb, const u16* __restrict__ Kb,
    const u16* __restrict__ Vt, u16* __restrict__ Ob) {
    __shared__ __align__(16) u16 sK[64 * 136];   // [kv][d], stride 136
    __shared__ __align__(16) u16 sV[128 * 72];   // [d][kv], stride 72
    __shared__ __align__(16) u16 sP[128 * 72];   // per-wave 32 rows [q][kv]

    int t = threadIdx.x, lane = t & 63, w = t >> 6;
    int r = lane & 15, qd = lane >> 4;
    int q0 = blockIdx.x * 128;
    int h = blockIdx.y;
    size_t bt0 = (size_t)blockIdx.z * 2048;

    // Q fragments: 32 q-rows per wave, A-layout A[m=lane&15][k=quad*8+j]
    bf16x8 qf[2][4];
#pragma unroll
    for (int mt = 0; mt < 2; ++mt) {
        const u16* qp = Qb + (bt0 + q0 + w * 32 + mt * 16 + r) * 4096 + h * 128 + qd * 8;
#pragma unroll
        for (int kk = 0; kk < 4; ++kk) qf[mt][kk] = *(const bf16x8*)(qp + kk * 32);
    }

    f32x4 o[2][8];
    float mrun[2][4], lrun[2][4];
#pragma unroll
    for (int mt = 0; mt < 2; ++mt) {
#pragma unroll
        for (int dn = 0; dn < 8; ++dn) o[mt][dn] = (f32x4){0.f, 0.f, 0.f, 0.f};
#pragma unroll
        for (int j = 0; j < 4; ++j) { mrun[mt][j] = -1e30f; lrun[mt][j] = 0.f; }
    }

    const float scale = 0.08838834764831845f;   // 1/sqrt(128)
    int e = t * 8;
    int krr = e >> 7, kcc = e & 127;
    int vdd = e >> 6, vkv = e & 63;
    int ktiles = q0 / 64 + 2;

    for (int kt = 0; kt < ktiles; ++kt) {
        int kb = kt * 64;
        const u16* kg = Kb + (bt0 + kb + krr) * 128 + kcc;
        u16* kl = sK + krr * 136 + kcc;
#pragma unroll
        for (int c = 0; c < 4; ++c)
            *(uint4*)(kl + c * 16 * 136) = *(const uint4*)(kg + (size_t)c * 16 * 128);
        const u16* vg = Vt + (size_t)vdd * 4096 + bt0 + kb + vkv;
        u16* vl = sV + vdd * 72 + vkv;
#pragma unroll
        for (int c = 0; c < 4; ++c)
            *(uint4*)(vl + c * 32 * 72) = *(const uint4*)(vg + (size_t)c * 32 * 4096);
        __syncthreads();

        // S = Q K^T (m=q, n=kv, k=d)
        f32x4 s[2][4];
#pragma unroll
        for (int mt = 0; mt < 2; ++mt)
#pragma unroll
            for (int nt = 0; nt < 4; ++nt) s[mt][nt] = (f32x4){0.f, 0.f, 0.f, 0.f};
#pragma unroll
        for (int kk = 0; kk < 4; ++kk) {
            bf16x8 kf[4];
#pragma unroll
            for (int nt = 0; nt < 4; ++nt)
                kf[nt] = *(const bf16x8*)(sK + (nt * 16 + r) * 136 + kk * 32 + qd * 8);
#pragma unroll
            for (int mt = 0; mt < 2; ++mt)
#pragma unroll
                for (int nt = 0; nt < 4; ++nt)
                    s[mt][nt] = __builtin_amdgcn_mfma_f32_16x16x32_bf16(qf[mt][kk], kf[nt], s[mt][nt], 0, 0, 0);
        }

        // online softmax (C row = quad*4+reg, col = lane&15)
#pragma unroll
        for (int mt = 0; mt < 2; ++mt) {
            int qrow0 = q0 + w * 32 + mt * 16 + qd * 4;
#pragma unroll
            for (int nt = 0; nt < 4; ++nt) {
                int kcol = kb + nt * 16 + r;
#pragma unroll
                for (int j = 0; j < 4; ++j) {
                    float sv = s[mt][nt][j] * scale;
                    s[mt][nt][j] = (kcol <= qrow0 + j) ? sv : -1e30f;
                }
            }
#pragma unroll
            for (int j = 0; j < 4; ++j) {
                float mx = fmaxf(fmaxf(s[mt][0][j], s[mt][1][j]), fmaxf(s[mt][2][j], s[mt][3][j]));
                mx = fmaxf(mx, __shfl_xor(mx, 1));
                mx = fmaxf(mx, __shfl_xor(mx, 2));
                mx = fmaxf(mx, __shfl_xor(mx, 4));
                mx = fmaxf(mx, __shfl_xor(mx, 8));
                float mnew = fmaxf(mrun[mt][j], mx);
                float alpha = exp2f((mrun[mt][j] - mnew) * LOG2E);
                mrun[mt][j] = mnew;
                float rs = 0.f;
                u16* pp = sP + (size_t)(w * 32 + mt * 16 + qd * 4 + j) * 72;
#pragma unroll
                for (int nt = 0; nt < 4; ++nt) {
                    float p = exp2f((s[mt][nt][j] - mnew) * LOG2E);
                    rs += p;
                    pp[nt * 16 + r] = f2b(p);
                }
                rs += __shfl_xor(rs, 1);
                rs += __shfl_xor(rs, 2);
                rs += __shfl_xor(rs, 4);
                rs += __shfl_xor(rs, 8);
                lrun[mt][j] = lrun[mt][j] * alpha + rs;
#pragma unroll
                for (int dn = 0; dn < 8; ++dn) o[mt][dn][j] *= alpha;
            }
        }

        __syncthreads();   // order sP stores vs sP vector reads

        // O += P V  (P from LDS in A-layout; V as Vt rows -> contiguous b128)
#pragma unroll
        for (int kk = 0; kk < 2; ++kk) {
            bf16x8 pf[2];
#pragma unroll
            for (int mt = 0; mt < 2; ++mt)
                pf[mt] = *(const bf16x8*)(sP + (w * 32 + mt * 16 + r) * 72 + kk * 32 + qd * 8);
#pragma unroll
            for (int dn = 0; dn < 8; ++dn) {
                bf16x8 vf = *(const bf16x8*)(sV + (dn * 16 + r) * 72 + kk * 32 + qd * 8);
#pragma unroll
                for (int mt = 0; mt < 2; ++mt)
                    o[mt][dn] = __builtin_amdgcn_mfma_f32_16x16x32_bf16(pf[mt], vf, o[mt][dn], 0, 0, 0);
            }
        }
        __syncthreads();   // before restaging sK/sV (also orders sP read(kt) vs write(kt+1))
    }

#pragma unroll
    for (int mt = 0; mt < 2; ++mt)
#pragma unroll
        for (int j = 0; j < 4; ++j) {
            float inv = 1.0f / lrun[mt][j];
            u16* op = Ob + (bt0 + q0 + w * 32 + mt * 16 + qd * 4 + j) * 4096 + h * 128;
#pragma unroll
            for (int dn = 0; dn < 8; ++dn) op[dn * 16 + r] = f2b(o[mt][dn][j] * inv);
        }
}

extern "C" void kernel_launch(void* const* d_in, const int* in_sizes, int n_in,
                              void* d_out, int out_size, void* d_ws, size_t ws_size,
                              hipStream_t stream) {
    const float* x   = (const float*)d_in[0];
    const float* wq  = (const float*)d_in[1];
    const float* wqb = (const float*)d_in[2];
    const float* wk  = (const float*)d_in[3];
    const float* wkb = (const float*)d_in[4];
    const float* wv  = (const float*)d_in[5];
    const float* wvb = (const float*)d_in[6];
    const float* wo  = (const float*)d_in[7];
    const float* wob = (const float*)d_in[8];

    const int NX = 4096 * 4096;   // x / wq / wo element counts
    const int NK = 128 * 4096;    // wk / wv element counts

    // workspace layout (u16 elements). Ob reuses xb's region, wo16 reuses wq16's.
    u16* xb   = (u16*)d_ws;                      // [0,   32MB)  4096x4096 bf16; later Ob
    u16* wq16 = xb   + (size_t)NX;               // [32,  64MB)  later wo16
    u16* wk16 = wq16 + (size_t)NX;               // [64,  65MB)
    u16* wv16 = wk16 + (size_t)NK;               // [65,  66MB)
    u16* Qb   = wv16 + (size_t)NK;               // [66,  98MB)  4096x4096
    u16* Kb   = Qb   + (size_t)NX;               // [98,  99MB)  4096x128
    u16* Vt   = Kb   + (size_t)NK;               // [99, 100MB)  128x4096 (transposed)
    u16* Ob   = xb;                              // alias (xb dead after qkv_gemm)
    u16* wo16 = wq16;                            // alias (wq16 dead after qkv_gemm)
    float* out = (float*)d_out;

    cvt_f32_bf16<<<NX / 2048, 256, 0, stream>>>(x,  xb,   NX);
    cvt_f32_bf16<<<NX / 2048, 256, 0, stream>>>(wq, wq16, NX);
    cvt_f32_bf16<<<NK / 2048, 256, 0, stream>>>(wk, wk16, NK);
    cvt_f32_bf16<<<NK / 2048, 256, 0, stream>>>(wv, wv16, NK);

    qkv_gemm<<<dim3(32, 34), 256, 0, stream>>>(xb, wq16, wqb, wk16, wkb, wv16, wvb, Qb, Kb, Vt);

    cvt_f32_bf16<<<NX / 2048, 256, 0, stream>>>(wo, wo16, NX);  // after qkv (region reuse)

    flash_mqa<<<dim3(16, 32, 2), 256, 0, stream>>>(Qb, Kb, Vt, Ob);
    out_gemm<<<dim3(32, 32), 256, 0, stream>>>(Ob, wo16, wob, out);
}

// Round 4
// 736.366 us; speedup vs baseline: 1.3922x; 1.3922x over previous
//
#include <hip/hip_runtime.h>

typedef unsigned short u16;
using bf16x8 = __attribute__((ext_vector_type(8))) __bf16;
using f32x4  = __attribute__((ext_vector_type(4))) float;

// B=2, T=2048, D=4096, H=32, HD=128, HKV=1. M = B*T = 4096 token rows.
// Inputs/outputs are FP32 (per reference). Internals are bf16 for MFMA.

__device__ __forceinline__ u16 f2b(float f) {
    union { float f; unsigned int i; } x; x.f = f;
    unsigned int i = x.i + (((x.i >> 16) & 1u) + 0x7fffu);  // RNE
    return (u16)(i >> 16);
}
// round-half-up: 2 VALU ops; used only for P in [0,1] (no NaN/sign issues)
__device__ __forceinline__ u16 f2b_ru(float f) {
    union { float f; unsigned int i; } x; x.f = f;
    return (u16)((x.i + 0x8000u) >> 16);
}
__device__ __forceinline__ void gload_lds16(const u16* g, u16* l) {
    __builtin_amdgcn_global_load_lds((const __attribute__((address_space(1))) void*)g,
                                     (__attribute__((address_space(3))) void*)l, 16, 0, 0);
}

// ---- fp32 -> bf16 conversion (vectorized, 8 elems/thread) ----
__global__ __launch_bounds__(256) void cvt_f32_bf16(const float* __restrict__ in,
                                                    u16* __restrict__ out, int n) {
    int i = (blockIdx.x * 256 + threadIdx.x) * 8;
    if (i >= n) return;
    float4 a = *(const float4*)(in + i);
    float4 b = *(const float4*)(in + i + 4);
    union { u16 u[8]; uint4 v; } o;
    o.u[0] = f2b(a.x); o.u[1] = f2b(a.y); o.u[2] = f2b(a.z); o.u[3] = f2b(a.w);
    o.u[4] = f2b(b.x); o.u[5] = f2b(b.y); o.u[6] = f2b(b.z); o.u[7] = f2b(b.w);
    *(uint4*)(out + i) = o.v;
}

// ---- m97-style 128x128 tile gemm_bt core: C = A(128xK) * W(128xK)^T, K=4096 ----
__device__ __forceinline__ void gemm_core(const u16* __restrict__ Atile,
                                          const u16* __restrict__ Wtile,
                                          f32x4 acc[4][4], u16* sA, u16* sB, int t) {
    const int K = 4096;
    int lane = t & 63, wave = t >> 6;
    int wm = (wave & 1) * 64, wn = (wave >> 1) * 64;
    int r = lane & 15, qd = lane >> 4;
    int e0 = t * 8;
    int sr0 = e0 >> 5;
    int sc0 = e0 & 31;
    for (int kt = 0; kt < K / 32; ++kt) {
        int k0 = kt * 32;
        gload_lds16(Atile + (size_t)sr0 * K + k0 + sc0,        sA + e0);
        gload_lds16(Atile + (size_t)(sr0 + 64) * K + k0 + sc0, sA + e0 + 2048);
        gload_lds16(Wtile + (size_t)sr0 * K + k0 + sc0,        sB + e0);
        gload_lds16(Wtile + (size_t)(sr0 + 64) * K + k0 + sc0, sB + e0 + 2048);
        __syncthreads();
        bf16x8 af[4], bfr[4];
#pragma unroll
        for (int mt = 0; mt < 4; ++mt) af[mt] = *(const bf16x8*)(sA + (wm + mt * 16 + r) * 32 + qd * 8);
#pragma unroll
        for (int nt = 0; nt < 4; ++nt) bfr[nt] = *(const bf16x8*)(sB + (wn + nt * 16 + r) * 32 + qd * 8);
#pragma unroll
        for (int mt = 0; mt < 4; ++mt)
#pragma unroll
            for (int nt = 0; nt < 4; ++nt)
                acc[mt][nt] = __builtin_amdgcn_mfma_f32_16x16x32_bf16(af[mt], bfr[nt], acc[mt][nt], 0, 0, 0);
        __syncthreads();
    }
}

// ---- fused QKV projection. grid (32, 34). col<32: Q (pre-scaled). col==32: K. col==33: V^T ----
__global__ __launch_bounds__(256) void qkv_gemm(
    const u16* __restrict__ x,
    const u16* __restrict__ wq, const float* __restrict__ wqb,
    const u16* __restrict__ wk, const float* __restrict__ wkb,
    const u16* __restrict__ wv, const float* __restrict__ wvb,
    u16* __restrict__ Qb, u16* __restrict__ Kb, u16* __restrict__ Vt) {
    __shared__ __align__(16) u16 sA[128 * 32];
    __shared__ __align__(16) u16 sB[128 * 32];
    int row0 = blockIdx.x * 128;
    int bn = blockIdx.y;
    const u16* W; const float* bias;
    if (bn < 32)       { W = wq + (size_t)bn * 128 * 4096; bias = wqb + bn * 128; }
    else if (bn == 32) { W = wk; bias = wkb; }
    else               { W = wv; bias = wvb; }
    int t = threadIdx.x;
    f32x4 acc[4][4];
#pragma unroll
    for (int mt = 0; mt < 4; ++mt)
#pragma unroll
        for (int nt = 0; nt < 4; ++nt) acc[mt][nt] = (f32x4){0.f, 0.f, 0.f, 0.f};
    gemm_core(x + (size_t)row0 * 4096, W, acc, sA, sB, t);
    int lane = t & 63, wave = t >> 6;
    int wm = (wave & 1) * 64, wn = (wave >> 1) * 64;
    int r = lane & 15, qd = lane >> 4;
    // fold softmax scale AND log2(e) into Q so flash uses exp2 with no multiplies
    const float QSCALE = 0.08838834764831845f * 1.4426950408889634f;
#pragma unroll
    for (int nt = 0; nt < 4; ++nt) {
        float bv = bias[wn + nt * 16 + r];
#pragma unroll
        for (int mt = 0; mt < 4; ++mt)
#pragma unroll
            for (int j = 0; j < 4; ++j) {
                float v = acc[mt][nt][j] + bv;
                int m = row0 + wm + mt * 16 + qd * 4 + j;
                int n = wn + nt * 16 + r;
                if (bn < 32)       Qb[(size_t)m * 4096 + bn * 128 + n] = f2b(v * QSCALE);
                else if (bn == 32) Kb[(size_t)m * 128 + n] = f2b(v);
                else               Vt[(size_t)n * 4096 + m] = f2b(v);   // transposed for flash PV
            }
    }
}

// ---- output projection: C(fp32) = A(bf16) * wo(bf16)^T + b(fp32). grid (32, 32) ----
__global__ __launch_bounds__(256) void out_gemm(
    const u16* __restrict__ A, const u16* __restrict__ W,
    const float* __restrict__ bias, float* __restrict__ C) {
    __shared__ __align__(16) u16 sA[128 * 32];
    __shared__ __align__(16) u16 sB[128 * 32];
    int row0 = blockIdx.x * 128;
    int col0 = blockIdx.y * 128;
    int t = threadIdx.x;
    f32x4 acc[4][4];
#pragma unroll
    for (int mt = 0; mt < 4; ++mt)
#pragma unroll
        for (int nt = 0; nt < 4; ++nt) acc[mt][nt] = (f32x4){0.f, 0.f, 0.f, 0.f};
    gemm_core(A + (size_t)row0 * 4096, W + (size_t)col0 * 4096, acc, sA, sB, t);
    int lane = t & 63, wave = t >> 6;
    int wm = (wave & 1) * 64, wn = (wave >> 1) * 64;
    int r = lane & 15, qd = lane >> 4;
#pragma unroll
    for (int nt = 0; nt < 4; ++nt) {
        float bv = bias[col0 + wn + nt * 16 + r];
#pragma unroll
        for (int mt = 0; mt < 4; ++mt)
#pragma unroll
            for (int j = 0; j < 4; ++j) {
                int m = row0 + wm + mt * 16 + qd * 4 + j;
                int n = col0 + wn + nt * 16 + r;
                C[(size_t)m * 4096 + n] = acc[mt][nt][j] + bv;
            }
    }
}

// ---- flash MQA attention. grid 1024 blocks; LPT remap: heavy q-tiles first ----
__global__ __launch_bounds__(256, 2) void flash_mqa(
    const u16* __restrict__ Qb, const u16* __restrict__ Kb,
    const u16* __restrict__ Vt, u16* __restrict__ Ob) {
    __shared__ __align__(16) u16 sK[64 * 136];   // [kv][d]
    __shared__ __align__(16) u16 sV[128 * 72];   // [d][kv]
    __shared__ __align__(16) u16 sP[128 * 72];   // [q][kv]

    int t = threadIdx.x, lane = t & 63, w = t >> 6;
    int r = lane & 15, qd = lane >> 4;

    // LPT remap: dispatcher issues low flat-ids first -> schedule heavy (qi=15) blocks first,
    // light (qi=0) blocks fill the tail. Performance-only permutation.
    int fid = blockIdx.x + 16 * blockIdx.y + 512 * blockIdx.z;
    int qi  = 15 - (fid >> 6);
    int rem = fid & 63;
    int h   = rem & 31;
    size_t bt0 = (size_t)(rem >> 5) * 2048;
    int q0 = qi * 128;

    // Q fragments (pre-scaled by scale*log2e): A-layout A[m=lane&15][k=quad*8+j]
    bf16x8 qf[2][4];
#pragma unroll
    for (int mt = 0; mt < 2; ++mt) {
        const u16* qp = Qb + (bt0 + q0 + w * 32 + mt * 16 + r) * 4096 + h * 128 + qd * 8;
#pragma unroll
        for (int kk = 0; kk < 4; ++kk) qf[mt][kk] = *(const bf16x8*)(qp + kk * 32);
    }

    f32x4 o[2][8], osum[2];
    float mrun[2][4];
#pragma unroll
    for (int mt = 0; mt < 2; ++mt) {
#pragma unroll
        for (int dn = 0; dn < 8; ++dn) o[mt][dn] = (f32x4){0.f, 0.f, 0.f, 0.f};
        osum[mt] = (f32x4){0.f, 0.f, 0.f, 0.f};
#pragma unroll
        for (int j = 0; j < 4; ++j) mrun[mt][j] = -1e30f;
    }

    // ones B-fragment for MFMA row-sum of P (l accumulation, replaces shuffle-reduce)
    union { uint4 v; bf16x8 b; } onesu;
    onesu.v = make_uint4(0x3F803F80u, 0x3F803F80u, 0x3F803F80u, 0x3F803F80u);
    const bf16x8 ones = onesu.b;

    int e = t * 8;
    int krr = e >> 7, kcc = e & 127;
    int vdd = e >> 6, vkv = e & 63;
    int ktiles = 2 * qi + 2;

    for (int kt = 0; kt < ktiles; ++kt) {
        int kb = kt * 64;
        const u16* kg = Kb + (bt0 + kb + krr) * 128 + kcc;
        u16* kl = sK + krr * 136 + kcc;
#pragma unroll
        for (int c = 0; c < 4; ++c)
            *(uint4*)(kl + c * 16 * 136) = *(const uint4*)(kg + (size_t)c * 16 * 128);
        const u16* vg = Vt + (size_t)vdd * 4096 + bt0 + kb + vkv;
        u16* vl = sV + vdd * 72 + vkv;
#pragma unroll
        for (int c = 0; c < 4; ++c)
            *(uint4*)(vl + c * 32 * 72) = *(const uint4*)(vg + (size_t)c * 32 * 4096);
        __syncthreads();

        // S = Q K^T (already in log2-units due to Q pre-scale)
        f32x4 s[2][4];
#pragma unroll
        for (int mt = 0; mt < 2; ++mt)
#pragma unroll
            for (int nt = 0; nt < 4; ++nt) s[mt][nt] = (f32x4){0.f, 0.f, 0.f, 0.f};
#pragma unroll
        for (int kk = 0; kk < 4; ++kk) {
            bf16x8 kf[4];
#pragma unroll
            for (int nt = 0; nt < 4; ++nt)
                kf[nt] = *(const bf16x8*)(sK + (nt * 16 + r) * 136 + kk * 32 + qd * 8);
#pragma unroll
            for (int mt = 0; mt < 2; ++mt)
#pragma unroll
                for (int nt = 0; nt < 4; ++nt)
                    s[mt][nt] = __builtin_amdgcn_mfma_f32_16x16x32_bf16(qf[mt][kk], kf[nt], s[mt][nt], 0, 0, 0);
        }

        // online softmax (C row = quad*4+reg, col = lane&15), all in exp2 domain
#pragma unroll
        for (int mt = 0; mt < 2; ++mt) {
            int qrow0 = q0 + w * 32 + mt * 16 + qd * 4;
#pragma unroll
            for (int nt = 0; nt < 4; ++nt) {
                int kcol = kb + nt * 16 + r;
#pragma unroll
                for (int j = 0; j < 4; ++j)
                    s[mt][nt][j] = (kcol <= qrow0 + j) ? s[mt][nt][j] : -1e30f;
            }
#pragma unroll
            for (int j = 0; j < 4; ++j) {
                float mx = fmaxf(fmaxf(s[mt][0][j], s[mt][1][j]), fmaxf(s[mt][2][j], s[mt][3][j]));
                mx = fmaxf(mx, __shfl_xor(mx, 1));
                mx = fmaxf(mx, __shfl_xor(mx, 2));
                mx = fmaxf(mx, __shfl_xor(mx, 4));
                mx = fmaxf(mx, __shfl_xor(mx, 8));
                float mnew = fmaxf(mrun[mt][j], mx);
                float alpha = exp2f(mrun[mt][j] - mnew);
                mrun[mt][j] = mnew;
                u16* pp = sP + (size_t)(w * 32 + mt * 16 + qd * 4 + j) * 72;
#pragma unroll
                for (int nt = 0; nt < 4; ++nt)
                    pp[nt * 16 + r] = f2b_ru(exp2f(s[mt][nt][j] - mnew));
#pragma unroll
                for (int dn = 0; dn < 8; ++dn) o[mt][dn][j] *= alpha;
                osum[mt][j] *= alpha;
            }
        }

        __syncthreads();   // order sP stores vs sP vector reads

        // O += P V; osum += P * ones (MFMA row-sum -> softmax denominator)
#pragma unroll
        for (int kk = 0; kk < 2; ++kk) {
            bf16x8 pf[2];
#pragma unroll
            for (int mt = 0; mt < 2; ++mt) {
                pf[mt] = *(const bf16x8*)(sP + (w * 32 + mt * 16 + r) * 72 + kk * 32 + qd * 8);
                osum[mt] = __builtin_amdgcn_mfma_f32_16x16x32_bf16(pf[mt], ones, osum[mt], 0, 0, 0);
            }
#pragma unroll
            for (int dn = 0; dn < 8; ++dn) {
                bf16x8 vf = *(const bf16x8*)(sV + (dn * 16 + r) * 72 + kk * 32 + qd * 8);
#pragma unroll
                for (int mt = 0; mt < 2; ++mt)
                    o[mt][dn] = __builtin_amdgcn_mfma_f32_16x16x32_bf16(pf[mt], vf, o[mt][dn], 0, 0, 0);
            }
        }
        __syncthreads();   // before restaging sK/sV (also orders sP read(kt) vs write(kt+1))
    }

#pragma unroll
    for (int mt = 0; mt < 2; ++mt)
#pragma unroll
        for (int j = 0; j < 4; ++j) {
            float inv = 1.0f / osum[mt][j];
            u16* op = Ob + (bt0 + q0 + w * 32 + mt * 16 + qd * 4 + j) * 4096 + h * 128;
#pragma unroll
            for (int dn = 0; dn < 8; ++dn) op[dn * 16 + r] = f2b(o[mt][dn][j] * inv);
        }
}

extern "C" void kernel_launch(void* const* d_in, const int* in_sizes, int n_in,
                              void* d_out, int out_size, void* d_ws, size_t ws_size,
                              hipStream_t stream) {
    const float* x   = (const float*)d_in[0];
    const float* wq  = (const float*)d_in[1];
    const float* wqb = (const float*)d_in[2];
    const float* wk  = (const float*)d_in[3];
    const float* wkb = (const float*)d_in[4];
    const float* wv  = (const float*)d_in[5];
    const float* wvb = (const float*)d_in[6];
    const float* wo  = (const float*)d_in[7];
    const float* wob = (const float*)d_in[8];

    const int NX = 4096 * 4096;   // x / wq / wo element counts
    const int NK = 128 * 4096;    // wk / wv element counts

    u16* xb   = (u16*)d_ws;                      // later Ob
    u16* wq16 = xb   + (size_t)NX;               // later wo16
    u16* wk16 = wq16 + (size_t)NX;
    u16* wv16 = wk16 + (size_t)NK;
    u16* Qb   = wv16 + (size_t)NK;
    u16* Kb   = Qb   + (size_t)NX;
    u16* Vt   = Kb   + (size_t)NK;
    u16* Ob   = xb;                              // alias (xb dead after qkv_gemm)
    u16* wo16 = wq16;                            // alias (wq16 dead after qkv_gemm)
    float* out = (float*)d_out;

    cvt_f32_bf16<<<NX / 2048, 256, 0, stream>>>(x,  xb,   NX);
    cvt_f32_bf16<<<NX / 2048, 256, 0, stream>>>(wq, wq16, NX);
    cvt_f32_bf16<<<NK / 2048, 256, 0, stream>>>(wk, wk16, NK);
    cvt_f32_bf16<<<NK / 2048, 256, 0, stream>>>(wv, wv16, NK);

    qkv_gemm<<<dim3(32, 34), 256, 0, stream>>>(xb, wq16, wqb, wk16, wkb, wv16, wvb, Qb, Kb, Vt);

    cvt_f32_bf16<<<NX / 2048, 256, 0, stream>>>(wo, wo16, NX);  // after qkv (region reuse)

    flash_mqa<<<dim3(16, 32, 2), 256, 0, stream>>>(Qb, Kb, Vt, Ob);
    out_gemm<<<dim3(32, 32), 256, 0, stream>>>(Ob, wo16, wob, out);
}